// Round 1
// baseline (1765.650 us; speedup 1.0000x reference)
//
#include <hip/hip_runtime.h>

// Problem constants (fixed by the reference file).
#define BN 2
#define NN 50000
#define EE 500000
#define DD 128
#define OO 128

// ---------------------------------------------------------------------------
// Stage 2: per-edge scatter of raw features.
// One wave (64 lanes) per edge; each lane owns 2 consecutive floats of the
// 128-float feature row (float2 = 8B/lane -> 512B coalesced per wave).
// unsafeAtomicAdd -> hardware global_atomic_add_f32 (no CAS loop).
// ---------------------------------------------------------------------------
__global__ __launch_bounds__(256) void scatter_k(
    const float* __restrict__ x,    // (BN, NN, DD)
    const int* __restrict__ ei,     // (2, EE)
    const float* __restrict__ ea,   // (EE, DD)
    float* __restrict__ S,          // (BN, NN, DD) accum
    float* __restrict__ T,          // (NN, DD) accum
    float* __restrict__ cnt)        // (NN,) accum
{
    int wid = (blockIdx.x * 256 + threadIdx.x) >> 6;   // edge id
    if (wid >= EE) return;
    int lane = threadIdx.x & 63;

    int src = ei[wid];        // wave-uniform -> scalar load
    int dst = ei[EE + wid];

    // edge_attr -> T[dst]
    float2 v = ((const float2*)(ea + (size_t)wid * DD))[lane];
    float* Trow = T + (size_t)dst * DD + 2 * lane;
    unsafeAtomicAdd(Trow, v.x);
    unsafeAtomicAdd(Trow + 1, v.y);

    // x[b, src] -> S[b, dst]
#pragma unroll
    for (int b = 0; b < BN; ++b) {
        float2 u = ((const float2*)(x + ((size_t)b * NN + src) * DD))[lane];
        float* Srow = S + ((size_t)b * NN + dst) * DD + 2 * lane;
        unsafeAtomicAdd(Srow, u.x);
        unsafeAtomicAdd(Srow + 1, u.y);
    }

    if (lane == 0) unsafeAtomicAdd(cnt + dst, 1.0f);
}

// ---------------------------------------------------------------------------
// Stage 3: fused node-level GEMMs.
//   messages[r] = (concat(S[r], c*x[r], T[n]) @ W_msg + c*b_msg) / max(c,1)
//   out[r]      = messages[r] @ W_upd + b_upd
// 64 rows x 128 cols per block, 256 threads, each thread 4x8 outputs.
// K=384 streamed in 12 tiles of 32; messages tile round-trips through LDS.
// ---------------------------------------------------------------------------
__global__ __launch_bounds__(256) void gemm_k(
    const float* __restrict__ S,
    const float* __restrict__ T,
    const float* __restrict__ cnt,
    const float* __restrict__ x,
    const float* __restrict__ Wm,   // (384, 128)
    const float* __restrict__ bm,   // (128,)
    const float* __restrict__ Wu,   // (128, 128)
    const float* __restrict__ bu,   // (128,)
    float* __restrict__ out)        // (BN*NN, 128)
{
    __shared__ float As[64][36];    // A tile (pad 36: float4-aligned rows)
    __shared__ float Ws[32][132];   // W tile (reused for W_upd)
    __shared__ float Ms[64][132];   // messages tile

    const int tid = threadIdx.x;
    const int R0  = blockIdx.x * 64;
    const int tr  = tid >> 4;          // 0..15  -> rows tr*4 .. tr*4+3
    const int tc  = tid & 15;          // 0..15  -> cols tc*8 .. tc*8+7
    const int tr4 = tr * 4;
    const int tc8 = tc * 8;

    // staging map: A-tile (64 rows x 32 k) -> 8 floats/thread
    const int sr = tid >> 2;           // 0..63 row
    const int sk = (tid & 3) * 8;      // 0,8,16,24
    const int Rs = R0 + sr;
    const bool svalid = Rs < BN * NN;
    const int ns = svalid ? (Rs % NN) : 0;
    // staging map: W-tile (32 x 128) -> 16 floats/thread
    const int wr = tid >> 3;           // 0..31
    const int wc = (tid & 7) * 16;     // 0..112

    float acc[4][8];
#pragma unroll
    for (int i = 0; i < 4; ++i)
#pragma unroll
        for (int j = 0; j < 8; ++j) acc[i][j] = 0.0f;

    for (int kt = 0; kt < 12; ++kt) {
        const int kg  = kt * 32;
        const int seg = kg >> 7;               // 0:S 1:c*x 2:T (tile never straddles)
        const int off = kg - seg * 128 + sk;

        // ---- stage A ----
        float4 a0 = {0, 0, 0, 0}, a1 = {0, 0, 0, 0};
        if (svalid) {
            if (seg == 0) {
                const float4* p = (const float4*)(S + (size_t)Rs * DD + off);
                a0 = p[0]; a1 = p[1];
            } else if (seg == 1) {
                const float c = cnt[ns];
                const float4* p = (const float4*)(x + (size_t)Rs * DD + off);
                a0 = p[0]; a1 = p[1];
                a0.x *= c; a0.y *= c; a0.z *= c; a0.w *= c;
                a1.x *= c; a1.y *= c; a1.z *= c; a1.w *= c;
            } else {
                const float4* p = (const float4*)(T + (size_t)ns * DD + off);
                a0 = p[0]; a1 = p[1];
            }
        }
        *(float4*)&As[sr][sk]     = a0;
        *(float4*)&As[sr][sk + 4] = a1;

        // ---- stage W_msg tile ----
        {
            const float4* wsrc = (const float4*)(Wm + (size_t)(kg + wr) * OO + wc);
            float4* wdst = (float4*)&Ws[wr][wc];
            wdst[0] = wsrc[0]; wdst[1] = wsrc[1];
            wdst[2] = wsrc[2]; wdst[3] = wsrc[3];
        }
        __syncthreads();

        // ---- compute ----
#pragma unroll 8
        for (int k = 0; k < 32; ++k) {
            const float a0v = As[tr4][k];
            const float a1v = As[tr4 + 1][k];
            const float a2v = As[tr4 + 2][k];
            const float a3v = As[tr4 + 3][k];
            const float4 w0 = *(const float4*)&Ws[k][tc8];
            const float4 w1 = *(const float4*)&Ws[k][tc8 + 4];
            const float wv[8] = {w0.x, w0.y, w0.z, w0.w, w1.x, w1.y, w1.z, w1.w};
#pragma unroll
            for (int j = 0; j < 8; ++j) {
                acc[0][j] += a0v * wv[j];
                acc[1][j] += a1v * wv[j];
                acc[2][j] += a2v * wv[j];
                acc[3][j] += a3v * wv[j];
            }
        }
        __syncthreads();
    }

    // ---- messages = (acc + c*b_msg) / max(c,1) -> Ms ----
    float bmv[8];
    {
        const float4 b0 = *(const float4*)(bm + tc8);
        const float4 b1 = *(const float4*)(bm + tc8 + 4);
        bmv[0]=b0.x; bmv[1]=b0.y; bmv[2]=b0.z; bmv[3]=b0.w;
        bmv[4]=b1.x; bmv[5]=b1.y; bmv[6]=b1.z; bmv[7]=b1.w;
    }
#pragma unroll
    for (int i = 0; i < 4; ++i) {
        const int Rr = R0 + tr4 + i;
        float c = 0.0f;
        if (Rr < BN * NN) c = cnt[Rr % NN];
        const float inv = 1.0f / fmaxf(c, 1.0f);
#pragma unroll
        for (int j = 0; j < 8; ++j)
            Ms[tr4 + i][tc8 + j] = (acc[i][j] + c * bmv[j]) * inv;
    }
    __syncthreads();

    // ---- out = Ms @ W_upd + b_upd ----
    float acc2[4][8];
#pragma unroll
    for (int i = 0; i < 4; ++i)
#pragma unroll
        for (int j = 0; j < 8; ++j) acc2[i][j] = 0.0f;

    for (int kt = 0; kt < 4; ++kt) {
        {
            const float4* wsrc = (const float4*)(Wu + (size_t)(kt * 32 + wr) * OO + wc);
            float4* wdst = (float4*)&Ws[wr][wc];
            wdst[0] = wsrc[0]; wdst[1] = wsrc[1];
            wdst[2] = wsrc[2]; wdst[3] = wsrc[3];
        }
        __syncthreads();
#pragma unroll 8
        for (int k = 0; k < 32; ++k) {
            const int kk = kt * 32 + k;
            const float a0v = Ms[tr4][kk];
            const float a1v = Ms[tr4 + 1][kk];
            const float a2v = Ms[tr4 + 2][kk];
            const float a3v = Ms[tr4 + 3][kk];
            const float4 w0 = *(const float4*)&Ws[k][tc8];
            const float4 w1 = *(const float4*)&Ws[k][tc8 + 4];
            const float wv[8] = {w0.x, w0.y, w0.z, w0.w, w1.x, w1.y, w1.z, w1.w};
#pragma unroll
            for (int j = 0; j < 8; ++j) {
                acc2[0][j] += a0v * wv[j];
                acc2[1][j] += a1v * wv[j];
                acc2[2][j] += a2v * wv[j];
                acc2[3][j] += a3v * wv[j];
            }
        }
        __syncthreads();
    }

    float buv[8];
    {
        const float4 b0 = *(const float4*)(bu + tc8);
        const float4 b1 = *(const float4*)(bu + tc8 + 4);
        buv[0]=b0.x; buv[1]=b0.y; buv[2]=b0.z; buv[3]=b0.w;
        buv[4]=b1.x; buv[5]=b1.y; buv[6]=b1.z; buv[7]=b1.w;
    }
#pragma unroll
    for (int i = 0; i < 4; ++i) {
        const int Rr = R0 + tr4 + i;
        if (Rr < BN * NN) {
            float4 o0, o1;
            o0.x = acc2[i][0] + buv[0]; o0.y = acc2[i][1] + buv[1];
            o0.z = acc2[i][2] + buv[2]; o0.w = acc2[i][3] + buv[3];
            o1.x = acc2[i][4] + buv[4]; o1.y = acc2[i][5] + buv[5];
            o1.z = acc2[i][6] + buv[6]; o1.w = acc2[i][7] + buv[7];
            *(float4*)(out + (size_t)Rr * OO + tc8)     = o0;
            *(float4*)(out + (size_t)Rr * OO + tc8 + 4) = o1;
        }
    }
}

extern "C" void kernel_launch(void* const* d_in, const int* in_sizes, int n_in,
                              void* d_out, int out_size, void* d_ws, size_t ws_size,
                              hipStream_t stream) {
    const float* x  = (const float*)d_in[0];
    const int*   ei = (const int*)d_in[1];
    const float* ea = (const float*)d_in[2];
    const float* Wm = (const float*)d_in[3];
    const float* bm = (const float*)d_in[4];
    const float* Wu = (const float*)d_in[5];
    const float* bu = (const float*)d_in[6];
    float* out = (float*)d_out;

    float* S   = (float*)d_ws;                       // BN*NN*DD
    float* T   = S + (size_t)BN * NN * DD;           // NN*DD
    float* cnt = T + (size_t)NN * DD;                // NN

    const size_t zero_floats = (size_t)BN * NN * DD + (size_t)NN * DD + NN;
    hipMemsetAsync(d_ws, 0, zero_floats * sizeof(float), stream);

    scatter_k<<<EE / 4, 256, 0, stream>>>(x, ei, ea, S, T, cnt);

    const int nblocks = (BN * NN + 63) / 64;
    gemm_k<<<nblocks, 256, 0, stream>>>(S, T, cnt, x, Wm, bm, Wu, bu, out);
}

// Round 2
// 798.900 us; speedup vs baseline: 2.2101x; 2.2101x over previous
//
#include <hip/hip_runtime.h>

// Problem constants (fixed by the reference file).
#define BN 2
#define NN 50000
#define EE 500000
#define DD 128
#define OO 128

// ---------------------------------------------------------------------------
// CSR build: histogram -> exclusive scan -> fill.
// ---------------------------------------------------------------------------
__global__ __launch_bounds__(256) void hist_k(const int* __restrict__ ei,
                                              int* __restrict__ hist) {
    int gid = blockIdx.x * 256 + threadIdx.x;
    if (gid >= EE) return;
    atomicAdd(&hist[ei[EE + gid]], 1);
}

__global__ __launch_bounds__(1024) void scan_k(const int* __restrict__ hist,
                                               int* __restrict__ offsets,
                                               int* __restrict__ cursor) {
    __shared__ int part[1024];
    const int t = threadIdx.x;
    const int CH = 49;                       // 1024*49 = 50176 >= NN
    const int start = t * CH;
    const int end = min(start + CH, NN);
    int s = 0;
    for (int i = start; i < end; ++i) s += hist[i];
    part[t] = s;
    __syncthreads();
    for (int off = 1; off < 1024; off <<= 1) {
        int v = (t >= off) ? part[t - off] : 0;
        __syncthreads();
        part[t] += v;
        __syncthreads();
    }
    int run = part[t] - s;                   // exclusive prefix of this chunk
    for (int i = start; i < end; ++i) {
        offsets[i] = run;
        cursor[i] = run;
        run += hist[i];
    }
    if (t == 1023) offsets[NN] = part[1023];
}

__global__ __launch_bounds__(256) void fill_k(const int* __restrict__ ei,
                                              int* __restrict__ cursor,
                                              int* __restrict__ eidx,
                                              int* __restrict__ esrc) {
    int gid = blockIdx.x * 256 + threadIdx.x;
    if (gid >= EE) return;
    int dst = ei[EE + gid];
    int pos = atomicAdd(&cursor[dst], 1);
    eidx[pos] = gid;
    esrc[pos] = ei[gid];
}

// ---------------------------------------------------------------------------
// Gather-aggregate: one wave per dst node. Lane owns float2 (2 of 128 feats).
// No fp32 atomics; S/T/cnt written with plain stores (no memset needed).
// ---------------------------------------------------------------------------
__global__ __launch_bounds__(256) void agg_k(
    const float* __restrict__ x,      // (BN, NN, DD)
    const float* __restrict__ ea,     // (EE, DD)
    const int* __restrict__ offsets,  // (NN+1)
    const int* __restrict__ eidx,     // (EE)
    const int* __restrict__ esrc,     // (EE)
    float* __restrict__ S,            // (BN, NN, DD)
    float* __restrict__ T,            // (NN, DD)
    float* __restrict__ cnt)          // (NN)
{
    const int n = (blockIdx.x * 256 + threadIdx.x) >> 6;
    if (n >= NN) return;
    const int lane = threadIdx.x & 63;

    const int beg = offsets[n];
    const int end = offsets[n + 1];

    float2 tA = {0, 0}, s0A = {0, 0}, s1A = {0, 0};

    int j = beg;
    for (; j + 1 < end; j += 2) {        // unroll x2 -> 6 outstanding loads
        int e0 = eidx[j], a0 = esrc[j];
        int e1 = eidx[j + 1], a1 = esrc[j + 1];
        float2 v0 = ((const float2*)(ea + (size_t)e0 * DD))[lane];
        float2 u00 = ((const float2*)(x + (size_t)a0 * DD))[lane];
        float2 u01 = ((const float2*)(x + ((size_t)NN + a0) * DD))[lane];
        float2 v1 = ((const float2*)(ea + (size_t)e1 * DD))[lane];
        float2 u10 = ((const float2*)(x + (size_t)a1 * DD))[lane];
        float2 u11 = ((const float2*)(x + ((size_t)NN + a1) * DD))[lane];
        tA.x += v0.x + v1.x;   tA.y += v0.y + v1.y;
        s0A.x += u00.x + u10.x; s0A.y += u00.y + u10.y;
        s1A.x += u01.x + u11.x; s1A.y += u01.y + u11.y;
    }
    if (j < end) {
        int e0 = eidx[j], a0 = esrc[j];
        float2 v0 = ((const float2*)(ea + (size_t)e0 * DD))[lane];
        float2 u00 = ((const float2*)(x + (size_t)a0 * DD))[lane];
        float2 u01 = ((const float2*)(x + ((size_t)NN + a0) * DD))[lane];
        tA.x += v0.x; tA.y += v0.y;
        s0A.x += u00.x; s0A.y += u00.y;
        s1A.x += u01.x; s1A.y += u01.y;
    }

    ((float2*)(T + (size_t)n * DD))[lane] = tA;
    ((float2*)(S + (size_t)n * DD))[lane] = s0A;
    ((float2*)(S + ((size_t)NN + n) * DD))[lane] = s1A;
    if (lane == 0) cnt[n] = (float)(end - beg);
}

// ---------------------------------------------------------------------------
// Fused node-level GEMMs (64 rows x 128 cols per block, 256 threads).
// LDS: Ws region + (As|Ms) overlapped region = 49.5 KB -> 3 blocks/CU.
// ---------------------------------------------------------------------------
__global__ __launch_bounds__(256, 3) void gemm_k(
    const float* __restrict__ S,
    const float* __restrict__ T,
    const float* __restrict__ cnt,
    const float* __restrict__ x,
    const float* __restrict__ Wm,   // (384, 128)
    const float* __restrict__ bm,   // (128,)
    const float* __restrict__ Wu,   // (128, 128)
    const float* __restrict__ bu,   // (128,)
    float* __restrict__ out)        // (BN*NN, 128)
{
    __shared__ float smem[32 * 132 + 64 * 132];   // Ws | (As or Ms)
    float* Ws   = smem;            // [32][132]
    float* AsMs = smem + 32 * 132; // As: [64][36] phase1 / Ms: [64][132] phase2

    const int tid = threadIdx.x;
    const int R0  = blockIdx.x * 64;
    const int tr4 = (tid >> 4) * 4;
    const int tc8 = (tid & 15) * 8;

    const int sr = tid >> 2;
    const int sk = (tid & 3) * 8;
    const int Rs = R0 + sr;
    const bool svalid = Rs < BN * NN;
    const int ns = svalid ? (Rs % NN) : 0;
    const int wr = tid >> 3;
    const int wc = (tid & 7) * 16;

    float acc[4][8];
#pragma unroll
    for (int i = 0; i < 4; ++i)
#pragma unroll
        for (int j = 0; j < 8; ++j) acc[i][j] = 0.0f;

    for (int kt = 0; kt < 12; ++kt) {
        const int kg  = kt * 32;
        const int seg = kg >> 7;
        const int off = kg - seg * 128 + sk;

        float4 a0 = {0, 0, 0, 0}, a1 = {0, 0, 0, 0};
        if (svalid) {
            if (seg == 0) {
                const float4* p = (const float4*)(S + (size_t)Rs * DD + off);
                a0 = p[0]; a1 = p[1];
            } else if (seg == 1) {
                const float c = cnt[ns];
                const float4* p = (const float4*)(x + (size_t)Rs * DD + off);
                a0 = p[0]; a1 = p[1];
                a0.x *= c; a0.y *= c; a0.z *= c; a0.w *= c;
                a1.x *= c; a1.y *= c; a1.z *= c; a1.w *= c;
            } else {
                const float4* p = (const float4*)(T + (size_t)ns * DD + off);
                a0 = p[0]; a1 = p[1];
            }
        }
        *(float4*)&AsMs[sr * 36 + sk]     = a0;
        *(float4*)&AsMs[sr * 36 + sk + 4] = a1;

        {
            const float4* wsrc = (const float4*)(Wm + (size_t)(kg + wr) * OO + wc);
            float4* wdst = (float4*)&Ws[wr * 132 + wc];
            wdst[0] = wsrc[0]; wdst[1] = wsrc[1];
            wdst[2] = wsrc[2]; wdst[3] = wsrc[3];
        }
        __syncthreads();

#pragma unroll 8
        for (int k = 0; k < 32; ++k) {
            const float a0v = AsMs[tr4 * 36 + k];
            const float a1v = AsMs[(tr4 + 1) * 36 + k];
            const float a2v = AsMs[(tr4 + 2) * 36 + k];
            const float a3v = AsMs[(tr4 + 3) * 36 + k];
            const float4 w0 = *(const float4*)&Ws[k * 132 + tc8];
            const float4 w1 = *(const float4*)&Ws[k * 132 + tc8 + 4];
            const float wv[8] = {w0.x, w0.y, w0.z, w0.w, w1.x, w1.y, w1.z, w1.w};
#pragma unroll
            for (int j = 0; j < 8; ++j) {
                acc[0][j] += a0v * wv[j];
                acc[1][j] += a1v * wv[j];
                acc[2][j] += a2v * wv[j];
                acc[3][j] += a3v * wv[j];
            }
        }
        __syncthreads();
    }

    // messages = (acc + c*b_msg) / max(c,1) -> Ms (overwrites As region)
    float bmv[8];
    {
        const float4 b0 = *(const float4*)(bm + tc8);
        const float4 b1 = *(const float4*)(bm + tc8 + 4);
        bmv[0]=b0.x; bmv[1]=b0.y; bmv[2]=b0.z; bmv[3]=b0.w;
        bmv[4]=b1.x; bmv[5]=b1.y; bmv[6]=b1.z; bmv[7]=b1.w;
    }
#pragma unroll
    for (int i = 0; i < 4; ++i) {
        const int Rr = R0 + tr4 + i;
        float c = 0.0f;
        if (Rr < BN * NN) c = cnt[Rr % NN];
        const float inv = 1.0f / fmaxf(c, 1.0f);
#pragma unroll
        for (int j = 0; j < 8; ++j)
            AsMs[(tr4 + i) * 132 + tc8 + j] = (acc[i][j] + c * bmv[j]) * inv;
    }

    float acc2[4][8];
#pragma unroll
    for (int i = 0; i < 4; ++i)
#pragma unroll
        for (int j = 0; j < 8; ++j) acc2[i][j] = 0.0f;

    for (int kt = 0; kt < 4; ++kt) {
        {
            const float4* wsrc = (const float4*)(Wu + (size_t)(kt * 32 + wr) * OO + wc);
            float4* wdst = (float4*)&Ws[wr * 132 + wc];
            wdst[0] = wsrc[0]; wdst[1] = wsrc[1];
            wdst[2] = wsrc[2]; wdst[3] = wsrc[3];
        }
        __syncthreads();
#pragma unroll 8
        for (int k = 0; k < 32; ++k) {
            const int kk = kt * 32 + k;
            const float a0v = AsMs[tr4 * 132 + kk];
            const float a1v = AsMs[(tr4 + 1) * 132 + kk];
            const float a2v = AsMs[(tr4 + 2) * 132 + kk];
            const float a3v = AsMs[(tr4 + 3) * 132 + kk];
            const float4 w0 = *(const float4*)&Ws[k * 132 + tc8];
            const float4 w1 = *(const float4*)&Ws[k * 132 + tc8 + 4];
            const float wv[8] = {w0.x, w0.y, w0.z, w0.w, w1.x, w1.y, w1.z, w1.w};
#pragma unroll
            for (int j = 0; j < 8; ++j) {
                acc2[0][j] += a0v * wv[j];
                acc2[1][j] += a1v * wv[j];
                acc2[2][j] += a2v * wv[j];
                acc2[3][j] += a3v * wv[j];
            }
        }
        __syncthreads();
    }

    float buv[8];
    {
        const float4 b0 = *(const float4*)(bu + tc8);
        const float4 b1 = *(const float4*)(bu + tc8 + 4);
        buv[0]=b0.x; buv[1]=b0.y; buv[2]=b0.z; buv[3]=b0.w;
        buv[4]=b1.x; buv[5]=b1.y; buv[6]=b1.z; buv[7]=b1.w;
    }
#pragma unroll
    for (int i = 0; i < 4; ++i) {
        const int Rr = R0 + tr4 + i;
        if (Rr < BN * NN) {
            float4 o0, o1;
            o0.x = acc2[i][0] + buv[0]; o0.y = acc2[i][1] + buv[1];
            o0.z = acc2[i][2] + buv[2]; o0.w = acc2[i][3] + buv[3];
            o1.x = acc2[i][4] + buv[4]; o1.y = acc2[i][5] + buv[5];
            o1.z = acc2[i][6] + buv[6]; o1.w = acc2[i][7] + buv[7];
            *(float4*)(out + (size_t)Rr * OO + tc8)     = o0;
            *(float4*)(out + (size_t)Rr * OO + tc8 + 4) = o1;
        }
    }
}

extern "C" void kernel_launch(void* const* d_in, const int* in_sizes, int n_in,
                              void* d_out, int out_size, void* d_ws, size_t ws_size,
                              hipStream_t stream) {
    const float* x  = (const float*)d_in[0];
    const int*   ei = (const int*)d_in[1];
    const float* ea = (const float*)d_in[2];
    const float* Wm = (const float*)d_in[3];
    const float* bm = (const float*)d_in[4];
    const float* Wu = (const float*)d_in[5];
    const float* bu = (const float*)d_in[6];
    float* out = (float*)d_out;

    // workspace layout (floats then ints, all 16B-aligned)
    float* S       = (float*)d_ws;                    // 12,800,000 f
    float* T       = S + (size_t)BN * NN * DD;        //  6,400,000 f
    float* cnt     = T + (size_t)NN * DD;             //     50,000 f
    int*   offsets = (int*)(cnt + NN);                //  50,004 i (NN+1 padded)
    int*   cursor  = offsets + 50004;                 //  50,000 i
    int*   hist    = cursor + NN;                     //  50,000 i
    int*   eidx    = hist + NN;                       // 500,000 i
    int*   esrc    = eidx + EE;                       // 500,000 i

    hipMemsetAsync(hist, 0, NN * sizeof(int), stream);

    hist_k<<<(EE + 255) / 256, 256, 0, stream>>>(ei, hist);
    scan_k<<<1, 1024, 0, stream>>>(hist, offsets, cursor);
    fill_k<<<(EE + 255) / 256, 256, 0, stream>>>(ei, cursor, eidx, esrc);

    agg_k<<<(NN + 3) / 4, 256, 0, stream>>>(x, ea, offsets, eidx, esrc, S, T, cnt);

    const int nblocks = (BN * NN + 63) / 64;
    gemm_k<<<nblocks, 256, 0, stream>>>(S, T, cnt, x, Wm, bm, Wu, bu, out);
}

// Round 4
// 642.741 us; speedup vs baseline: 2.7471x; 1.2430x over previous
//
#include <hip/hip_runtime.h>

// Problem constants (fixed by the reference file).
#define BN 2
#define NN 50000
#define EE 500000
#define DD 128
#define OO 128

typedef float f2v __attribute__((ext_vector_type(2)));

// ---------------------------------------------------------------------------
// Wf = W_msg @ W_upd (384x128), bmu = b_msg @ W_upd (128).
// ---------------------------------------------------------------------------
__global__ __launch_bounds__(128) void wfuse_k(
    const float* __restrict__ Wm, const float* __restrict__ Wu,
    const float* __restrict__ bm, float* __restrict__ Wf,
    float* __restrict__ bmu) {
    const int o = threadIdx.x;
    const int k = blockIdx.x;
    float s = 0.0f;
    if (k < 3 * DD) {
#pragma unroll 4
        for (int j = 0; j < OO; ++j) s += Wm[k * OO + j] * Wu[j * OO + o];
        Wf[k * OO + o] = s;
    } else {
#pragma unroll 4
        for (int j = 0; j < OO; ++j) s += bm[j] * Wu[j * OO + o];
        bmu[o] = s;
    }
}

// ---------------------------------------------------------------------------
// CSR build: histogram -> 3-phase parallel scan -> fill (packed int2).
// ---------------------------------------------------------------------------
__global__ __launch_bounds__(256) void hist_k(const int* __restrict__ ei,
                                              int* __restrict__ hist) {
    int gid = blockIdx.x * 256 + threadIdx.x;
    if (gid >= EE) return;
    atomicAdd(&hist[ei[EE + gid]], 1);
}

__global__ __launch_bounds__(256) void scan1_k(const int* __restrict__ hist,
                                               int* __restrict__ bsum) {
    int i = blockIdx.x * 256 + threadIdx.x;
    int v = (i < NN) ? hist[i] : 0;
#pragma unroll
    for (int off = 32; off > 0; off >>= 1) v += __shfl_down(v, off);
    __shared__ int ws[4];
    if ((threadIdx.x & 63) == 0) ws[threadIdx.x >> 6] = v;
    __syncthreads();
    if (threadIdx.x == 0) bsum[blockIdx.x] = ws[0] + ws[1] + ws[2] + ws[3];
}

__global__ __launch_bounds__(256) void scan2_k(const int* __restrict__ bsum,
                                               int* __restrict__ ebsum,
                                               int* __restrict__ offsets,
                                               int nblk) {
    __shared__ int s[256];
    const int t = threadIdx.x;
    int v = (t < nblk) ? bsum[t] : 0;
    s[t] = v;
    __syncthreads();
    for (int off = 1; off < 256; off <<= 1) {
        int u = (t >= off) ? s[t - off] : 0;
        __syncthreads();
        s[t] += u;
        __syncthreads();
    }
    ebsum[t] = s[t] - v;
    if (t == 0) offsets[NN] = EE;
}

__global__ __launch_bounds__(256) void scan3_k(const int* __restrict__ hist,
                                               const int* __restrict__ ebsum,
                                               int* __restrict__ offsets,
                                               int* __restrict__ cursor) {
    __shared__ int s[256];
    const int t = threadIdx.x;
    const int i = blockIdx.x * 256 + t;
    int v = (i < NN) ? hist[i] : 0;
    s[t] = v;
    __syncthreads();
    for (int off = 1; off < 256; off <<= 1) {
        int u = (t >= off) ? s[t - off] : 0;
        __syncthreads();
        s[t] += u;
        __syncthreads();
    }
    int ex = s[t] - v + ebsum[blockIdx.x];
    if (i < NN) { offsets[i] = ex; cursor[i] = ex; }
}

__global__ __launch_bounds__(256) void fill_k(const int* __restrict__ ei,
                                              int* __restrict__ cursor,
                                              int2* __restrict__ ep) {
    int gid = blockIdx.x * 256 + threadIdx.x;
    if (gid >= EE) return;
    int dst = ei[EE + gid];
    int pos = atomicAdd(&cursor[dst], 1);
    ep[pos] = make_int2(gid, ei[gid]);
}

// ---------------------------------------------------------------------------
// Gather-aggregate: one wave per dst node, lane owns float2. Unroll x4.
// ea streamed with nontemporal loads (protect x's LLC residency).
// ---------------------------------------------------------------------------
__global__ __launch_bounds__(256) void agg_k(
    const float* __restrict__ x,      // (BN, NN, DD)
    const float* __restrict__ ea,     // (EE, DD)
    const int* __restrict__ offsets,  // (NN+1)
    const int2* __restrict__ ep,      // (EE) {edge, src}
    float* __restrict__ S,            // (BN, NN, DD)
    float* __restrict__ T,            // (NN, DD)
    float* __restrict__ cnt)          // (NN)
{
    const int n = (blockIdx.x * 256 + threadIdx.x) >> 6;
    if (n >= NN) return;
    const int lane = threadIdx.x & 63;

    const int beg = offsets[n];
    const int end = offsets[n + 1];

    f2v tA = {0, 0}, s0A = {0, 0}, s1A = {0, 0};

    int j = beg;
    for (; j + 3 < end; j += 4) {
        int2 p0 = ep[j], p1 = ep[j + 1], p2 = ep[j + 2], p3 = ep[j + 3];
        f2v v0 = __builtin_nontemporal_load((const f2v*)(ea + (size_t)p0.x * DD) + lane);
        f2v v1 = __builtin_nontemporal_load((const f2v*)(ea + (size_t)p1.x * DD) + lane);
        f2v v2 = __builtin_nontemporal_load((const f2v*)(ea + (size_t)p2.x * DD) + lane);
        f2v v3 = __builtin_nontemporal_load((const f2v*)(ea + (size_t)p3.x * DD) + lane);
        f2v a0 = ((const f2v*)(x + (size_t)p0.y * DD))[lane];
        f2v a1 = ((const f2v*)(x + (size_t)p1.y * DD))[lane];
        f2v a2 = ((const f2v*)(x + (size_t)p2.y * DD))[lane];
        f2v a3 = ((const f2v*)(x + (size_t)p3.y * DD))[lane];
        f2v b0 = ((const f2v*)(x + ((size_t)NN + p0.y) * DD))[lane];
        f2v b1 = ((const f2v*)(x + ((size_t)NN + p1.y) * DD))[lane];
        f2v b2 = ((const f2v*)(x + ((size_t)NN + p2.y) * DD))[lane];
        f2v b3 = ((const f2v*)(x + ((size_t)NN + p3.y) * DD))[lane];
        tA  += v0 + v1 + v2 + v3;
        s0A += a0 + a1 + a2 + a3;
        s1A += b0 + b1 + b2 + b3;
    }
    for (; j < end; ++j) {
        int2 p = ep[j];
        f2v v = __builtin_nontemporal_load((const f2v*)(ea + (size_t)p.x * DD) + lane);
        f2v a = ((const f2v*)(x + (size_t)p.y * DD))[lane];
        f2v b = ((const f2v*)(x + ((size_t)NN + p.y) * DD))[lane];
        tA += v; s0A += a; s1A += b;
    }

    ((f2v*)(T + (size_t)n * DD))[lane] = tA;
    ((f2v*)(S + (size_t)n * DD))[lane] = s0A;
    ((f2v*)(S + ((size_t)NN + n) * DD))[lane] = s1A;
    if (lane == 0) cnt[n] = (float)(end - beg);
}

// ---------------------------------------------------------------------------
// Single fused GEMM: out = diag(1/max(c,1)) * (A @ Wf) + (c>0)*bmu + bu
// A = [S | c*x | T] built on the fly. 64 rows x 128 cols per block.
// Ast: transposed A tile [k][row], k-dependent +16 row rotation (mod 64)
//      -> 2-way-max LDS access on both write and read (free per m136).
// W cols per thread: {c0, 64+c0} -> 2-way (free) b128 reads.
// ---------------------------------------------------------------------------
__global__ __launch_bounds__(256, 4) void gemm_k(
    const float* __restrict__ S,
    const float* __restrict__ T,
    const float* __restrict__ cnt,
    const float* __restrict__ x,
    const float* __restrict__ Wf,   // (384, 128)
    const float* __restrict__ bmu,  // (128,)
    const float* __restrict__ bu,   // (128,)
    float* __restrict__ out)        // (BN*NN, 128)
{
    __shared__ float Ast[32 * 64];     // [k][row] swizzled, 8 KB
    __shared__ float Ws[32 * 132];     // [k][col] padded,  16.9 KB

    const int tid = threadIdx.x;
    const int R0  = blockIdx.x * 64;
    const int tr4 = (tid >> 4) * 4;          // rows tr4..tr4+3
    const int c0  = (tid & 15) * 4;          // cols c0..c0+3 and 64+c0..+3

    // A staging map: row sr, local k sk..sk+7
    const int sr = tid >> 2;
    const int sk = (tid & 3) * 8;
    const int Rs = R0 + sr;
    const bool svalid = Rs < BN * NN;
    const int ns = svalid ? (Rs < NN ? Rs : Rs - NN) : 0;
    const int rw = (sr + ((sk & 8) ? 16 : 0)) & 63;   // swizzled row for writes
    // W staging map
    const int wr = tid >> 3;
    const int wc = (tid & 7) * 16;

    float acc[4][8];
#pragma unroll
    for (int i = 0; i < 4; ++i)
#pragma unroll
        for (int j = 0; j < 8; ++j) acc[i][j] = 0.0f;

    for (int kt = 0; kt < 12; ++kt) {
        const int kg  = kt * 32;
        const int seg = kg >> 7;               // 0:S 1:c*x 2:T
        const int off = kg - seg * 128 + sk;

        float4 a0 = {0, 0, 0, 0}, a1 = {0, 0, 0, 0};
        if (svalid) {
            if (seg == 0) {
                const float4* p = (const float4*)(S + (size_t)Rs * DD + off);
                a0 = p[0]; a1 = p[1];
            } else if (seg == 1) {
                const float c = cnt[ns];
                const float4* p = (const float4*)(x + (size_t)Rs * DD + off);
                a0 = p[0]; a1 = p[1];
                a0.x *= c; a0.y *= c; a0.z *= c; a0.w *= c;
                a1.x *= c; a1.y *= c; a1.z *= c; a1.w *= c;
            } else {
                const float4* p = (const float4*)(T + (size_t)ns * DD + off);
                a0 = p[0]; a1 = p[1];
            }
        }
        {
            const float av[8] = {a0.x, a0.y, a0.z, a0.w, a1.x, a1.y, a1.z, a1.w};
#pragma unroll
            for (int i = 0; i < 8; ++i)
                Ast[(sk + i) * 64 + rw] = av[i];
        }
        {
            const float4* wsrc = (const float4*)(Wf + (size_t)(kg + wr) * OO + wc);
            float4* wdst = (float4*)&Ws[wr * 132 + wc];
            wdst[0] = wsrc[0]; wdst[1] = wsrc[1];
            wdst[2] = wsrc[2]; wdst[3] = wsrc[3];
        }
        __syncthreads();

#pragma unroll 8
        for (int k = 0; k < 32; ++k) {
            // FIX R3->R4: wrap the swizzled row index mod 64 (tr4+16 can
            // exceed 63 for tr4>=48; 4-aligned so the float4 never straddles
            // the wrap boundary).
            const int ar = (tr4 + ((k & 8) ? 16 : 0)) & 63;
            const float4 a  = *(const float4*)&Ast[k * 64 + ar];
            const float4 w0 = *(const float4*)&Ws[k * 132 + c0];
            const float4 w1 = *(const float4*)&Ws[k * 132 + c0 + 64];
            const float av[4] = {a.x, a.y, a.z, a.w};
            const float wv[8] = {w0.x, w0.y, w0.z, w0.w, w1.x, w1.y, w1.z, w1.w};
#pragma unroll
            for (int i = 0; i < 4; ++i)
#pragma unroll
                for (int j = 0; j < 8; ++j)
                    acc[i][j] += av[i] * wv[j];
        }
        __syncthreads();
    }

    // epilogue
    float4 bm0 = *(const float4*)(bmu + c0);
    float4 bm1 = *(const float4*)(bmu + 64 + c0);
    float4 bu0 = *(const float4*)(bu + c0);
    float4 bu1 = *(const float4*)(bu + 64 + c0);
#pragma unroll
    for (int i = 0; i < 4; ++i) {
        const int Rr = R0 + tr4 + i;
        if (Rr < BN * NN) {
            const int nr = (Rr < NN) ? Rr : Rr - NN;
            const float c = cnt[nr];
            const float inv = 1.0f / fmaxf(c, 1.0f);
            const float g = (c > 0.0f) ? 1.0f : 0.0f;
            float4 o0, o1;
            o0.x = acc[i][0] * inv + g * bm0.x + bu0.x;
            o0.y = acc[i][1] * inv + g * bm0.y + bu0.y;
            o0.z = acc[i][2] * inv + g * bm0.z + bu0.z;
            o0.w = acc[i][3] * inv + g * bm0.w + bu0.w;
            o1.x = acc[i][4] * inv + g * bm1.x + bu1.x;
            o1.y = acc[i][5] * inv + g * bm1.y + bu1.y;
            o1.z = acc[i][6] * inv + g * bm1.z + bu1.z;
            o1.w = acc[i][7] * inv + g * bm1.w + bu1.w;
            *(float4*)(out + (size_t)Rr * OO + c0)      = o0;
            *(float4*)(out + (size_t)Rr * OO + 64 + c0) = o1;
        }
    }
}

extern "C" void kernel_launch(void* const* d_in, const int* in_sizes, int n_in,
                              void* d_out, int out_size, void* d_ws, size_t ws_size,
                              hipStream_t stream) {
    const float* x  = (const float*)d_in[0];
    const int*   ei = (const int*)d_in[1];
    const float* ea = (const float*)d_in[2];
    const float* Wm = (const float*)d_in[3];
    const float* bm = (const float*)d_in[4];
    const float* Wu = (const float*)d_in[5];
    const float* bu = (const float*)d_in[6];
    float* out = (float*)d_out;

    // workspace layout
    float* S       = (float*)d_ws;                    // 12,800,000 f
    float* T       = S + (size_t)BN * NN * DD;        //  6,400,000 f
    float* cnt     = T + (size_t)NN * DD;             //     50,000 f
    float* Wf      = cnt + NN;                        //     49,152 f
    float* bmu     = Wf + 3 * DD * OO;                //        128 f
    int*   offsets = (int*)(bmu + OO);                //     50,004 i
    int*   cursor  = offsets + 50004;                 //     50,000 i
    int*   hist    = cursor + NN;                     //     50,000 i
    int*   bsum    = hist + NN;                       //        256 i
    int*   ebsum   = bsum + 256;                      //        256 i
    int2*  ep      = (int2*)(ebsum + 256);            //    500,000 int2

    const int nscan = (NN + 255) / 256;               // 196

    hipMemsetAsync(hist, 0, NN * sizeof(int), stream);

    wfuse_k<<<3 * DD + 1, 128, 0, stream>>>(Wm, Wu, bm, Wf, bmu);
    hist_k<<<(EE + 255) / 256, 256, 0, stream>>>(ei, hist);
    scan1_k<<<nscan, 256, 0, stream>>>(hist, bsum);
    scan2_k<<<1, 256, 0, stream>>>(bsum, ebsum, offsets, nscan);
    scan3_k<<<nscan, 256, 0, stream>>>(hist, ebsum, offsets, cursor);
    fill_k<<<(EE + 255) / 256, 256, 0, stream>>>(ei, cursor, ep);

    agg_k<<<(NN + 3) / 4, 256, 0, stream>>>(x, ea, offsets, ep, S, T, cnt);

    const int nblocks = (BN * NN + 63) / 64;
    gemm_k<<<nblocks, 256, 0, stream>>>(S, T, cnt, x, Wf, bmu, bu, out);
}